// Round 7
// baseline (514.477 us; speedup 1.0000x reference)
//
#include <hip/hip_runtime.h>
#include <cstdint>
#include <cstddef>

// ---------------------------------------------------------------------------
// ChunkedCrossAttention: h(4,2048,1024), e(4,32,2,128,1024)
// Pipeline (8 dispatches):
//   1. prep          = weight transpose/cast + LN (LN out -> VtG[0:16M])
//   2. qproj_cast    = Q-projection (512 blocks) + cast e-quarter0 (4096 blk)
//   3-6. gemm_kv256  = KV GEMM quarter i (blocks 0..255, 1/CU) FUSED with
//                      cast of quarter i+1 (blocks 256..2303) -> stg ping-pong
//                      (Di reads stg[i&1], casts q_{i+1} into stg[(i+1)&1])
//   7. attn          = one wave per head-job
//   8. O-proj + shifted residual + folded head_copy
// KV GEMM: proven 256x256 8-phase template (T2 swizzle + T3/T4 counted vmcnt
// + T5 setprio, stage 2/2/2/2). Workspace exactly 184 MiB.
// ---------------------------------------------------------------------------

typedef float f32x4 __attribute__((ext_vector_type(4)));
typedef __bf16 bf16x8 __attribute__((ext_vector_type(8)));

static __device__ __forceinline__ ushort f2bf(float f) {
  union { float f; uint32_t u; } x; x.f = f;
  uint32_t r = x.u + 0x7fffu + ((x.u >> 16) & 1u);   // RTNE
  return (ushort)(r >> 16);
}

static __device__ __forceinline__ bf16x8 ld_frag(const ushort* p) {
  union { uint4 u; bf16x8 v; } x;
  x.u = *(const uint4*)p;
  return x.v;
}

// async global->LDS, 16 B per lane (proven working).
static __device__ __forceinline__ void gl2lds16(const ushort* g, ushort* l) {
  __builtin_amdgcn_global_load_lds(
      (const __attribute__((address_space(1))) void*)g,
      (__attribute__((address_space(3))) void*)l,
      16, 0, 0);
}

// ---------------------------------------------------------------------------
// prep: blocks 0..1023  -> weight transpose+cast (z = bx>>8 selects W)
//       blocks 1024..   -> LayerNorm rows (LN out -> lnout, padded w/ zeros)
// ---------------------------------------------------------------------------
__global__ __launch_bounds__(256) void prep_kernel(const float* __restrict__ Wq,
                                                   const float* __restrict__ Wk,
                                                   const float* __restrict__ Wv,
                                                   const float* __restrict__ Wo,
                                                   const float* __restrict__ h,
                                                   const float* __restrict__ gamma,
                                                   const float* __restrict__ beta,
                                                   ushort* __restrict__ WqT,
                                                   ushort* __restrict__ WkvT,
                                                   ushort* __restrict__ WoT,
                                                   ushort* __restrict__ lnout) {
  __shared__ float tile[64][65];
  __shared__ float a1[4], a2[4];
  const int t = threadIdx.x;
  const int bx = blockIdx.x;

  if (bx < 1024) {                       // ---- weight transpose + cast ----
    const int z = bx >> 8, rem = bx & 255;
    const int n0 = (rem & 15) * 64, k0 = (rem >> 4) * 64;
    const float* W; ushort* WT;
    switch (z) {
      case 0:  W = Wq; WT = WqT; break;
      case 1:  W = Wk; WT = WkvT; break;
      case 2:  W = Wv; WT = WkvT + (size_t)1024 * 1024; break;
      default: W = Wo; WT = WoT; break;
    }
#pragma unroll
    for (int i = 0; i < 4; ++i) {
      int lid = i * 256 + t;
      int r = lid >> 4, c4 = (lid & 15) * 4;
      float4 v = *(const float4*)&W[(size_t)(k0 + r) * 1024 + n0 + c4];
      tile[r][c4 + 0] = v.x; tile[r][c4 + 1] = v.y;
      tile[r][c4 + 2] = v.z; tile[r][c4 + 3] = v.w;
    }
    __syncthreads();
#pragma unroll
    for (int i = 0; i < 4; ++i) {
      int lid = i * 256 + t;
      int n = lid >> 4, k4 = (lid & 15) * 4;
      ushort4 o;
      o.x = f2bf(tile[k4 + 0][n]); o.y = f2bf(tile[k4 + 1][n]);
      o.z = f2bf(tile[k4 + 2][n]); o.w = f2bf(tile[k4 + 3][n]);
      *(ushort4*)&WT[(size_t)(n0 + n) * 1024 + k0 + k4] = o;
    }
    return;
  }

  // ---- LayerNorm: lnout[b, s, :] = LN(h[b, 63+s, :]) for s<1985 else 0 ----
  const int bx2 = bx - 1024;
  const int b = bx2 >> 11, s = bx2 & 2047;
  ushort* orow = lnout + (size_t)(b * 2048 + s) * 1024;
  if (s >= 1985) {
    ushort4 z4; z4.x = 0; z4.y = 0; z4.z = 0; z4.w = 0;
    *(ushort4*)&orow[t * 4] = z4;
    return;
  }
  const float* xrow = h + (size_t)(b * 2048 + 63 + s) * 1024;
  float4 x = *(const float4*)&xrow[t * 4];
  float s1 = x.x + x.y + x.z + x.w;
  float s2 = x.x * x.x + x.y * x.y + x.z * x.z + x.w * x.w;
#pragma unroll
  for (int off = 32; off > 0; off >>= 1) {
    s1 += __shfl_xor(s1, off);
    s2 += __shfl_xor(s2, off);
  }
  if ((t & 63) == 0) { a1[t >> 6] = s1; a2[t >> 6] = s2; }
  __syncthreads();
  s1 = a1[0] + a1[1] + a1[2] + a1[3];
  s2 = a2[0] + a2[1] + a2[2] + a2[3];
  const float mu = s1 * (1.0f / 1024.0f);
  const float var = s2 * (1.0f / 1024.0f) - mu * mu;
  const float rstd = rsqrtf(var + 1e-5f);
  float4 g = *(const float4*)&gamma[t * 4];
  float4 be = *(const float4*)&beta[t * 4];
  ushort4 o;
  o.x = f2bf((x.x - mu) * rstd * g.x + be.x);
  o.y = f2bf((x.y - mu) * rstd * g.y + be.y);
  o.z = f2bf((x.z - mu) * rstd * g.z + be.z);
  o.w = f2bf((x.w - mu) * rstd * g.w + be.w);
  *(ushort4*)&orow[t * 4] = o;
}

// ---------------------------------------------------------------------------
// qproj_cast: blocks <512 = Q projection (128x128 GEMM, bf16 out, scale
// folded = 1/8*log2e); blocks >=512 = e-quarter0 cast f32->bf16 (4096 blk).
// Q-proj A (LN out) lives in VtG[0:16M]; cast writes stg[0:16M] -> disjoint.
// ---------------------------------------------------------------------------
__global__ __launch_bounds__(256) void qproj_cast(const ushort* __restrict__ A,
                                                  const ushort* __restrict__ Bt,
                                                  const float* __restrict__ bias,
                                                  ushort* __restrict__ Cbf,
                                                  float scale,
                                                  const float* __restrict__ ex,
                                                  ushort* __restrict__ ey) {
  if (blockIdx.x >= 512) {               // ---- cast path (quarter 0) ----
    const size_t i = ((size_t)(blockIdx.x - 512) * 256 + threadIdx.x) * 8;
    float4 a = *(const float4*)&ex[i];
    float4 b = *(const float4*)&ex[i + 4];
    ushort o[8];
    o[0] = f2bf(a.x); o[1] = f2bf(a.y); o[2] = f2bf(a.z); o[3] = f2bf(a.w);
    o[4] = f2bf(b.x); o[5] = f2bf(b.y); o[6] = f2bf(b.z); o[7] = f2bf(b.w);
    *(uint4*)&ey[i] = *(const uint4*)o;
    return;
  }
  // ---- Q-proj GEMM path (identical to proven gemm_bf16 MODE0, NT=8) ----
  __shared__ __align__(16) ushort Alds[2][128 * 32];
  __shared__ __align__(16) ushort Blds[2][128 * 32];
  const int t = threadIdx.x;
  const int lane = t & 63, wave = t >> 6;
  const int quad = lane >> 4, l16 = lane & 15;

  const int L = blockIdx.x;
  const int xcd = L & 7, slot = L >> 3;
  const int nt = slot & 7;
  const int mt = xcd * 8 + (slot >> 3);
  const int m0 = mt * 128, n0 = nt * 128;

  const int srow = lane >> 2;
  const int scol = (lane & 3) * 8;
  const int c0 = wave * 2;
  const ushort* gA0 = A  + (size_t)(m0 + c0 * 16 + srow) * 1024 + scol;
  const ushort* gA1 = gA0 + 16 * 1024;
  const ushort* gB0 = Bt + (size_t)(n0 + c0 * 16 + srow) * 1024 + scol;
  const ushort* gB1 = gB0 + 16 * 1024;
  ushort* dA0 = &Alds[0][c0 * 512 + lane * 8];
  ushort* dA1 = dA0 + 512;
  ushort* dB0 = &Blds[0][c0 * 512 + lane * 8];
  ushort* dB1 = dB0 + 512;
  const ptrdiff_t SUB = 128 * 32;

  const int wrow = (wave >> 1) * 64, wcol = (wave & 1) * 64;
  const ushort* pA = &Alds[0][(wrow + l16) * 32 + quad * 8];
  const ushort* pB = &Blds[0][(wcol + l16) * 32 + quad * 8];

  f32x4 zero = {0.f, 0.f, 0.f, 0.f};
  f32x4 acc[4][4];
#pragma unroll
  for (int i = 0; i < 4; ++i)
#pragma unroll
    for (int j = 0; j < 4; ++j) acc[i][j] = zero;

  for (int kb = 0; kb < 16; ++kb) {
    const int ko = kb * 64;
    gl2lds16(gA0 + ko, dA0);         gl2lds16(gA1 + ko, dA1);
    gl2lds16(gA0 + ko + 32, dA0 + SUB); gl2lds16(gA1 + ko + 32, dA1 + SUB);
    gl2lds16(gB0 + ko, dB0);         gl2lds16(gB1 + ko, dB1);
    gl2lds16(gB0 + ko + 32, dB0 + SUB); gl2lds16(gB1 + ko + 32, dB1 + SUB);
    __syncthreads();
#pragma unroll
    for (int sub = 0; sub < 2; ++sub) {
      bf16x8 af[4], bfv[4];
#pragma unroll
      for (int i = 0; i < 4; ++i) af[i]  = ld_frag(pA + sub * SUB + i * 512);
#pragma unroll
      for (int j = 0; j < 4; ++j) bfv[j] = ld_frag(pB + sub * SUB + j * 512);
#pragma unroll
      for (int i = 0; i < 4; ++i)
#pragma unroll
        for (int j = 0; j < 4; ++j)
          acc[i][j] = __builtin_amdgcn_mfma_f32_16x16x32_bf16(af[i], bfv[j], acc[i][j], 0, 0, 0);
    }
    __syncthreads();
  }

#pragma unroll
  for (int mi = 0; mi < 4; ++mi)
#pragma unroll
    for (int mj = 0; mj < 4; ++mj) {
      const int cc = n0 + wcol + mj * 16 + l16;
      const int r0 = m0 + wrow + mi * 16 + quad * 4;
      const float bvb = bias[cc];
#pragma unroll
      for (int rr = 0; rr < 4; ++rr)
        Cbf[(size_t)(r0 + rr) * 1024 + cc] = f2bf((acc[mi][mj][rr] + bvb) * scale);
    }
}

// ---------------------------------------------------------------------------
// 128x128 GEMM: O-proj, f32 out with shifted residual add; blocks >= 512
// perform the head-rows residual copy (folded head_copy).
// ---------------------------------------------------------------------------
__global__ __launch_bounds__(256) void gemm_oproj(const ushort* __restrict__ A,
                                                  const ushort* __restrict__ Bt,
                                                  const float* __restrict__ bias,
                                                  float* __restrict__ Cf,
                                                  const float* __restrict__ resid) {
  if (blockIdx.x >= 512) {       // folded head_copy: rows 0..62 per batch
    const int idx4 = (blockIdx.x - 512) * 256 + threadIdx.x;  // 0..64511
    const int b = idx4 / 16128;
    const int rem = idx4 - b * 16128;
    const size_t o = (size_t)b * 2048 * 1024 + (size_t)rem * 4;
    *(float4*)&Cf[o] = *(const float4*)&resid[o];
    return;
  }
  __shared__ __align__(16) ushort Alds[2][128 * 32];
  __shared__ __align__(16) ushort Blds[2][128 * 32];
  const int t = threadIdx.x;
  const int lane = t & 63, wave = t >> 6;
  const int quad = lane >> 4, l16 = lane & 15;

  const int L = blockIdx.x;
  const int xcd = L & 7, slot = L >> 3;
  const int nt = slot & 7;
  const int mt = xcd * 8 + (slot >> 3);
  const int m0 = mt * 128, n0 = nt * 128;

  const int srow = lane >> 2;
  const int scol = (lane & 3) * 8;
  const int c0 = wave * 2;
  const ushort* gA0 = A  + (size_t)(m0 + c0 * 16 + srow) * 1024 + scol;
  const ushort* gA1 = gA0 + 16 * 1024;
  const ushort* gB0 = Bt + (size_t)(n0 + c0 * 16 + srow) * 1024 + scol;
  const ushort* gB1 = gB0 + 16 * 1024;
  ushort* dA0 = &Alds[0][c0 * 512 + lane * 8];
  ushort* dA1 = dA0 + 512;
  ushort* dB0 = &Blds[0][c0 * 512 + lane * 8];
  ushort* dB1 = dB0 + 512;
  const ptrdiff_t SUB = 128 * 32;

  const int wrow = (wave >> 1) * 64, wcol = (wave & 1) * 64;
  const ushort* pA = &Alds[0][(wrow + l16) * 32 + quad * 8];
  const ushort* pB = &Blds[0][(wcol + l16) * 32 + quad * 8];

  f32x4 zero = {0.f, 0.f, 0.f, 0.f};
  f32x4 acc[4][4];
#pragma unroll
  for (int i = 0; i < 4; ++i)
#pragma unroll
    for (int j = 0; j < 4; ++j) acc[i][j] = zero;

  for (int kb = 0; kb < 16; ++kb) {
    const int ko = kb * 64;
    gl2lds16(gA0 + ko, dA0);         gl2lds16(gA1 + ko, dA1);
    gl2lds16(gA0 + ko + 32, dA0 + SUB); gl2lds16(gA1 + ko + 32, dA1 + SUB);
    gl2lds16(gB0 + ko, dB0);         gl2lds16(gB1 + ko, dB1);
    gl2lds16(gB0 + ko + 32, dB0 + SUB); gl2lds16(gB1 + ko + 32, dB1 + SUB);
    __syncthreads();
#pragma unroll
    for (int sub = 0; sub < 2; ++sub) {
      bf16x8 af[4], bfv[4];
#pragma unroll
      for (int i = 0; i < 4; ++i) af[i]  = ld_frag(pA + sub * SUB + i * 512);
#pragma unroll
      for (int j = 0; j < 4; ++j) bfv[j] = ld_frag(pB + sub * SUB + j * 512);
#pragma unroll
      for (int i = 0; i < 4; ++i)
#pragma unroll
        for (int j = 0; j < 4; ++j)
          acc[i][j] = __builtin_amdgcn_mfma_f32_16x16x32_bf16(af[i], bfv[j], acc[i][j], 0, 0, 0);
    }
    __syncthreads();
  }

#pragma unroll
  for (int mi = 0; mi < 4; ++mi)
#pragma unroll
    for (int mj = 0; mj < 4; ++mj) {
      const int cc = n0 + wcol + mj * 16 + l16;
      const int r0 = m0 + wrow + mi * 16 + quad * 4;
      const float bvb = bias[cc];
#pragma unroll
      for (int rr = 0; rr < 4; ++rr) {
        const int r = r0 + rr;
        const int b = r >> 11, s = r & 2047;
        if (s < 1985) {
          const size_t o = (size_t)(b * 2048 + s + 63) * 1024 + cc;
          Cf[o] = acc[mi][mj][rr] + bvb + resid[o];
        }
      }
    }
}

// ---------------------------------------------------------------------------
// Fused KV GEMM quarter + next-quarter cast.
//   blocks 0..255    : 256x256 8-phase KV GEMM on 8192-row quarter (1/CU)
//   blocks 256..2303 : cast e-quarter(i+1) f32->bf16 (rides in spare wave
//                      slots: KV = 8 waves + 128K LDS; cast = 0 LDS)
// KV template unchanged (T2 swizzle + T3/T4 counted vmcnt(6) + T5, 2/2/2/2).
// ---------------------------------------------------------------------------
__global__ __launch_bounds__(512, 2) void gemm_kv256(const ushort* __restrict__ A,
                                                     const ushort* __restrict__ Bt,
                                                     const float* __restrict__ bk_,
                                                     const float* __restrict__ bv_,
                                                     ushort* __restrict__ Kout,
                                                     ushort* __restrict__ Vtg,
                                                     int mrow_off,
                                                     const float* __restrict__ ecast_src,
                                                     ushort* __restrict__ ecast_dst) {
  if (blockIdx.x >= 256) {               // ---- cast path (next quarter) ----
    const size_t i = ((size_t)(blockIdx.x - 256) * 512 + threadIdx.x) * 8;
    float4 a = *(const float4*)&ecast_src[i];
    float4 b = *(const float4*)&ecast_src[i + 4];
    ushort o[8];
    o[0] = f2bf(a.x); o[1] = f2bf(a.y); o[2] = f2bf(a.z); o[3] = f2bf(a.w);
    o[4] = f2bf(b.x); o[5] = f2bf(b.y); o[6] = f2bf(b.z); o[7] = f2bf(b.w);
    *(uint4*)&ecast_dst[i] = *(const uint4*)o;
    return;
  }

  __shared__ __align__(16) ushort Alds[4 * 8192];   // 64 KiB
  __shared__ __align__(16) ushort Blds[4 * 8192];   // 64 KiB

  const int t = threadIdx.x;
  const int lane = t & 63, wave = t >> 6;          // 8 waves
  const int wm = wave >> 2, wn = wave & 3;         // 2 x 4
  const int l16 = lane & 15, quad = lane >> 4;

  const int L = blockIdx.x;                        // 0..255
  const int xcd = L & 7, slot = L >> 3;            // slot 0..31
  const int nt = slot & 7, mt = xcd * 4 + (slot >> 3);   // mtiles = 32
  const int m0 = mt * 256, n0 = nt * 256;

  // staging geometry (inverse-swizzled global source, linear LDS dest)
  const int w2 = wave * 2;
  const int srow = lane >> 3;                       // 0..7
  const int lanex = (lane & 7) ^ srow;              // inverse swizzle
  const ushort* gA2 = A  + (size_t)(m0 + w2 * 8 + srow) * 1024 + lanex * 8;
  const ushort* gB2 = Bt + (size_t)(n0 + w2 * 8 + srow) * 1024 + lanex * 8;
  ushort* dA2 = Alds + w2 * 512 + lane * 8;
  ushort* dB2 = Blds + w2 * 512 + lane * 8;

  auto stage_a = [&](int ti, int hh) {
    const ushort* g = gA2 + (size_t)hh * 131072 + (size_t)ti * 64;
    ushort* d = dA2 + ((ti & 1) * 2 + hh) * 8192;
    gl2lds16(g, d);
    gl2lds16(g + 8192, d + 512);
  };
  auto stage_b = [&](int ti, int hh) {
    const ushort* g = gB2 + (size_t)hh * 131072 + (size_t)ti * 64;
    ushort* d = dB2 + ((ti & 1) * 2 + hh) * 8192;
    gl2lds16(g, d);
    gl2lds16(g + 8192, d + 512);
  };

  // read geometry (swizzled): col = (ks^b2)*32 + (quad^(l16&3))*8
  const int b2 = (l16 >> 2) & 1;
  const int qx = (quad ^ (l16 & 3)) << 3;
  const int kof0 = b2 << 5;
  const int kof1 = 32 - kof0;

  f32x4 zero = {0.f, 0.f, 0.f, 0.f};
  f32x4 acc[8][4];
#pragma unroll
  for (int i = 0; i < 8; ++i)
#pragma unroll
    for (int j = 0; j < 4; ++j) acc[i][j] = zero;

  // prologue: tile 0 fully + B0/A0/B1 of tile 1
  stage_b(0, 0); stage_a(0, 0); stage_b(0, 1); stage_a(0, 1);
  stage_b(1, 0); stage_a(1, 0); stage_b(1, 1);
  asm volatile("s_waitcnt vmcnt(6)" ::: "memory");
  __builtin_amdgcn_s_barrier();

  bf16x8 a[4][2], b01[2][2], b23[2][2];

#pragma unroll 2
  for (int tt = 0; tt < 16; ++tt) {
    const int cur = tt & 1;
    const ushort* pa = Alds + (cur * 2 + wm) * 8192 + l16 * 64 + qx;
    const ushort* pb = Blds + (cur * 2 + (wn >> 1)) * 8192 +
                       ((wn & 1) * 64 + l16) * 64 + qx;

    // ================= phase 0: A(mi0-3), B(ni0-1); stage A1(t+1) ========
#pragma unroll
    for (int mi = 0; mi < 4; ++mi) {
      a[mi][0] = ld_frag(pa + mi * 1024 + kof0);
      a[mi][1] = ld_frag(pa + mi * 1024 + kof1);
    }
#pragma unroll
    for (int ni = 0; ni < 2; ++ni) {
      b01[ni][0] = ld_frag(pb + ni * 1024 + kof0);
      b01[ni][1] = ld_frag(pb + ni * 1024 + kof1);
    }
    if (tt < 15) stage_a(tt + 1, 1);
    __builtin_amdgcn_s_barrier();
    asm volatile("s_waitcnt lgkmcnt(0)" ::: "memory");
    __builtin_amdgcn_sched_barrier(0);
    __builtin_amdgcn_s_setprio(1);
#pragma unroll
    for (int mi = 0; mi < 4; ++mi)
#pragma unroll
      for (int ni = 0; ni < 2; ++ni) {
        acc[mi][ni] = __builtin_amdgcn_mfma_f32_16x16x32_bf16(a[mi][0], b01[ni][0], acc[mi][ni], 0, 0, 0);
        acc[mi][ni] = __builtin_amdgcn_mfma_f32_16x16x32_bf16(a[mi][1], b01[ni][1], acc[mi][ni], 0, 0, 0);
      }
    __builtin_amdgcn_s_setprio(0);
    __builtin_amdgcn_s_barrier();

    // ================= phase 1: B(ni2-3); stage B0(t+2) ==================
#pragma unroll
    for (int ni = 0; ni < 2; ++ni) {
      b23[ni][0] = ld_frag(pb + (ni + 2) * 1024 + kof0);
      b23[ni][1] = ld_frag(pb + (ni + 2) * 1024 + kof1);
    }
    if (tt < 14) stage_b(tt + 2, 0);
    __builtin_amdgcn_s_barrier();
    asm volatile("s_waitcnt lgkmcnt(0)" ::: "memory");
    __builtin_amdgcn_sched_barrier(0);
    __builtin_amdgcn_s_setprio(1);
#pragma unroll
    for (int mi = 0; mi < 4; ++mi)
#pragma unroll
      for (int ni = 0; ni < 2; ++ni) {
        acc[mi][ni + 2] = __builtin_amdgcn_mfma_f32_16x16x32_bf16(a[mi][0], b23[ni][0], acc[mi][ni + 2], 0, 0, 0);
        acc[mi][ni + 2] = __builtin_amdgcn_mfma_f32_16x16x32_bf16(a[mi][1], b23[ni][1], acc[mi][ni + 2], 0, 0, 0);
      }
    __builtin_amdgcn_s_setprio(0);
    __builtin_amdgcn_s_barrier();

    // ================= phase 2: A(mi4-7); stage B1(t+2) ==================
#pragma unroll
    for (int mi = 0; mi < 4; ++mi) {
      a[mi][0] = ld_frag(pa + (mi + 4) * 1024 + kof0);
      a[mi][1] = ld_frag(pa + (mi + 4) * 1024 + kof1);
    }
    if (tt < 14) stage_b(tt + 2, 1);
    __builtin_amdgcn_s_barrier();
    asm volatile("s_waitcnt lgkmcnt(0)" ::: "memory");
    __builtin_amdgcn_sched_barrier(0);
    __builtin_amdgcn_s_setprio(1);
#pragma unroll
    for (int mi = 0; mi < 4; ++mi)
#pragma unroll
      for (int ni = 0; ni < 2; ++ni) {
        acc[mi + 4][ni + 2] = __builtin_amdgcn_mfma_f32_16x16x32_bf16(a[mi][0], b23[ni][0], acc[mi + 4][ni + 2], 0, 0, 0);
        acc[mi + 4][ni + 2] = __builtin_amdgcn_mfma_f32_16x16x32_bf16(a[mi][1], b23[ni][1], acc[mi + 4][ni + 2], 0, 0, 0);
      }
    __builtin_amdgcn_s_setprio(0);
    __builtin_amdgcn_s_barrier();

    // ================= phase 3: no reads; stage A0(t+2) ==================
    if (tt < 14) stage_a(tt + 2, 0);
    __builtin_amdgcn_s_barrier();
    __builtin_amdgcn_s_setprio(1);
#pragma unroll
    for (int mi = 0; mi < 4; ++mi)
#pragma unroll
      for (int ni = 0; ni < 2; ++ni) {
        acc[mi + 4][ni] = __builtin_amdgcn_mfma_f32_16x16x32_bf16(a[mi][0], b01[ni][0], acc[mi + 4][ni], 0, 0, 0);
        acc[mi + 4][ni] = __builtin_amdgcn_mfma_f32_16x16x32_bf16(a[mi][1], b01[ni][1], acc[mi + 4][ni], 0, 0, 0);
      }
    __builtin_amdgcn_s_setprio(0);
    // K-tile boundary: counted vmcnt, never 0 in steady state
    if (tt < 15) {
      if (tt == 14) asm volatile("s_waitcnt vmcnt(0)" ::: "memory");
      else          asm volatile("s_waitcnt vmcnt(6)" ::: "memory");
      __builtin_amdgcn_s_barrier();
    }
  }

  // ---- epilogue ----
  const int rbase = m0 + wm * 128 + quad * 4;
  const int cbase = n0 + wn * 64 + l16;
  if (n0 < 1024) {   // K half: row-major bf16 + bk
#pragma unroll
    for (int mi = 0; mi < 8; ++mi)
#pragma unroll
      for (int ni = 0; ni < 4; ++ni) {
        const int cc = cbase + ni * 16;
        const float bb = bk_[cc];
        const int r0 = rbase + mi * 16;
#pragma unroll
        for (int rr = 0; rr < 4; ++rr)
          Kout[(size_t)(r0 + rr) * 1024 + cc] = f2bf(acc[mi][ni][rr] + bb);
      }
  } else {           // V half: transposed per head + bv
#pragma unroll
    for (int mi = 0; mi < 8; ++mi)
#pragma unroll
      for (int ni = 0; ni < 4; ++ni) {
        const int cv = cbase - 1024 + ni * 16;
        const int hh_ = cv >> 6, dd = cv & 63;
        const float bb = bv_[cv];
        const int gr0 = rbase + mi * 16 + mrow_off;
        const int bcl = gr0 >> 8, j0 = gr0 & 255;
        ushort4 o;
        o.x = f2bf(acc[mi][ni][0] + bb);
        o.y = f2bf(acc[mi][ni][1] + bb);
        o.z = f2bf(acc[mi][ni][2] + bb);
        o.w = f2bf(acc[mi][ni][3] + bb);
        *(ushort4*)&Vtg[(size_t)(bcl * 16 + hh_) * 16384 + dd * 256 + j0] = o;
      }
  }
}

// ---------------------------------------------------------------------------
// Attention: ONE WAVE per (b,chunk,head). 512 blocks x 4 independent waves,
// zero barriers. Swapped QK^T, online softmax, P via private per-wave LDS.
// ---------------------------------------------------------------------------
__global__ __launch_bounds__(256, 2) void attn_kernel(const ushort* __restrict__ Qb,
                                                      const ushort* __restrict__ Kb,
                                                      const ushort* __restrict__ Vtg,
                                                      ushort* __restrict__ Ob) {
  __shared__ __align__(16) ushort Plds[4][4096];    // 8 KiB per wave, private

  const int t = threadIdx.x;
  const int lane = t & 63, wave = t >> 6;
  const int quad = lane >> 4, l16 = lane & 15;
  const int hw = blockIdx.x * 4 + wave;             // 0..2047 head-jobs
  const int hd = hw & 15, c = (hw >> 4) & 31, b = hw >> 9;

  const int qrow0 = b * 2048 + c * 64;
  const int kvrow0 = (b * 32 + c) * 256;
  const int colh = hd * 64;
  const ushort* vsrc = Vtg + ((size_t)((b * 32 + c) * 16 + hd)) * 16384;
  char* pw = (char*)&Plds[wave][0];
  const int swz = (l16 & 7) << 4;

  // ---- Q fragments (B-operand): qf[qq][cc] = Q[qq*16+l16][cc*32+quad*8..]
  bf16x8 qf[4][2];
#pragma unroll
  for (int qq = 0; qq < 4; ++qq)
#pragma unroll
    for (int cc = 0; cc < 2; ++cc)
      qf[qq][cc] = ld_frag(&Qb[(size_t)(qrow0 + qq * 16 + l16) * 1024 +
                               colh + cc * 32 + quad * 8]);

  f32x4 zero = {0.f, 0.f, 0.f, 0.f};
  f32x4 Ot[4][4];                                   // [dd][qq], O^T frags
#pragma unroll
  for (int dd = 0; dd < 4; ++dd)
#pragma unroll
    for (int qq = 0; qq < 4; ++qq) Ot[dd][qq] = zero;
  float m[4], l[4];
#pragma unroll
  for (int qq = 0; qq < 4; ++qq) { m[qq] = -1e30f; l[qq] = 0.f; }

  for (int kb = 0; kb < 4; ++kb) {
    // ---- K fragments (A-operand) ----
    bf16x8 kf[4][2];
#pragma unroll
    for (int kk = 0; kk < 4; ++kk)
#pragma unroll
      for (int cc = 0; cc < 2; ++cc)
        kf[kk][cc] = ld_frag(&Kb[(size_t)(kvrow0 + kb * 64 + kk * 16 + l16) * 1024 +
                                 colh + cc * 32 + quad * 8]);

    // ---- St = K Q^T : col=l16=q, row=quad*4+rr=key-within-16 ----
    f32x4 st[4][4];
#pragma unroll
    for (int kk = 0; kk < 4; ++kk)
#pragma unroll
      for (int qq = 0; qq < 4; ++qq) st[kk][qq] = zero;
#pragma unroll
    for (int cc = 0; cc < 2; ++cc)
#pragma unroll
      for (int kk = 0; kk < 4; ++kk)
#pragma unroll
        for (int qq = 0; qq < 4; ++qq)
          st[kk][qq] = __builtin_amdgcn_mfma_f32_16x16x32_bf16(kf[kk][cc], qf[qq][cc], st[kk][qq], 0, 0, 0);

    // ---- V fragments (A-operand for PV); latency hides under softmax ----
    bf16x8 vf[4][2];
#pragma unroll
    for (int dd = 0; dd < 4; ++dd)
#pragma unroll
      for (int cc = 0; cc < 2; ++cc)
        vf[dd][cc] = ld_frag(&vsrc[(dd * 16 + l16) * 256 + kb * 64 + cc * 32 + quad * 8]);

    // ---- online softmax per qq (q = qq*16 + l16) ----
#pragma unroll
    for (int qq = 0; qq < 4; ++qq) {
      float bm = st[0][qq][0];
#pragma unroll
      for (int kk = 0; kk < 4; ++kk)
#pragma unroll
        for (int rr = 0; rr < 4; ++rr) bm = fmaxf(bm, st[kk][qq][rr]);
      bm = fmaxf(bm, __shfl_xor(bm, 16));
      bm = fmaxf(bm, __shfl_xor(bm, 32));
      const float mn = fmaxf(m[qq], bm);
      const float sc = exp2f(m[qq] - mn);
      float bs = 0.f;
#pragma unroll
      for (int kk = 0; kk < 4; ++kk)
#pragma unroll
        for (int rr = 0; rr < 4; ++rr) {
          float p = exp2f(st[kk][qq][rr] - mn);
          st[kk][qq][rr] = p;
          bs += p;
        }
      bs += __shfl_xor(bs, 16);
      bs += __shfl_xor(bs, 32);
      l[qq] = l[qq] * sc + bs;
      m[qq] = mn;
#pragma unroll
      for (int dd = 0; dd < 4; ++dd) Ot[dd][qq] *= sc;
      // P -> LDS at [q][key], swizzled
      const int rowb = (qq * 16 + l16) * 128;
#pragma unroll
      for (int kk = 0; kk < 4; ++kk) {
        uint32_t w0 = (uint32_t)f2bf(st[kk][qq][0]) | ((uint32_t)f2bf(st[kk][qq][1]) << 16);
        uint32_t w1 = (uint32_t)f2bf(st[kk][qq][2]) | ((uint32_t)f2bf(st[kk][qq][3]) << 16);
        const int byte = rowb + ((kk * 32 + quad * 8) ^ swz);
        *(uint32_t*)(pw + byte) = w0;
        *(uint32_t*)(pw + byte + 4) = w1;
      }
    }

    // ---- PV: Ot[dd][qq] += V^T x P ----
#pragma unroll
    for (int qq = 0; qq < 4; ++qq)
#pragma unroll
      for (int cc = 0; cc < 2; ++cc) {
        const int byte = (qq * 16 + l16) * 128 + ((cc * 64 + quad * 16) ^ swz);
        bf16x8 pf = ld_frag((const ushort*)(pw + byte));
#pragma unroll
        for (int dd = 0; dd < 4; ++dd)
          Ot[dd][qq] = __builtin_amdgcn_mfma_f32_16x16x32_bf16(vf[dd][cc], pf, Ot[dd][qq], 0, 0, 0);
      }
  }

  // ---- epilogue: normalize, transpose via LDS (P tile dead), store ----
#pragma unroll
  for (int qq = 0; qq < 4; ++qq) {
    const float inv = 1.0f / l[qq];
    const int rowb = (qq * 16 + l16) * 128;
#pragma unroll
    for (int dd = 0; dd < 4; ++dd) {
      f32x4 v = Ot[dd][qq];
      uint32_t w0 = (uint32_t)f2bf(v[0] * inv) | ((uint32_t)f2bf(v[1] * inv) << 16);
      uint32_t w1 = (uint32_t)f2bf(v[2] * inv) | ((uint32_t)f2bf(v[3] * inv) << 16);
      const int byte = rowb + ((dd * 32 + quad * 8) ^ swz);
      *(uint32_t*)(pw + byte) = w0;
      *(uint32_t*)(pw + byte + 4) = w1;
    }
  }
  // coalesced readout: 8 passes x (8 rows x 8 chunks of 16 B)
#pragma unroll
  for (int p = 0; p < 8; ++p) {
    const int r = p * 8 + (lane >> 3);
    const int ch = lane & 7;
    const int byte = r * 128 + ((ch * 16) ^ ((r & 7) << 4));
    uint4 o = *(const uint4*)(pw + byte);
    *(uint4*)&Ob[(size_t)(qrow0 + r) * 1024 + colh + ch * 8] = o;
  }
}

// ---------------------------------------------------------------------------
extern "C" void kernel_launch(void* const* d_in, const int* in_sizes, int n_in,
                              void* d_out, int out_size, void* d_ws, size_t ws_size,
                              hipStream_t stream) {
  const float* h     = (const float*)d_in[0];
  const float* e     = (const float*)d_in[1];
  const float* Wq    = (const float*)d_in[2];
  const float* bq    = (const float*)d_in[3];
  const float* Wk    = (const float*)d_in[4];
  const float* bk    = (const float*)d_in[5];
  const float* Wv    = (const float*)d_in[6];
  const float* bv    = (const float*)d_in[7];
  const float* Wo    = (const float*)d_in[8];
  const float* bo    = (const float*)d_in[9];
  const float* gamma = (const float*)d_in[10];
  const float* beta  = (const float*)d_in[11];
  float* out = (float*)d_out;

  // Workspace layout (exactly 184 MiB, proven safe):
  char* ws = (char*)d_ws;
  ushort* stg  = (ushort*)(ws + ((size_t)0 << 20));    // 32 MiB: 2x16M ping-pong
  ushort* WqT  = (ushort*)(ws + ((size_t)32 << 20));   // 2 MiB
  ushort* WkvT = (ushort*)(ws + ((size_t)34 << 20));   // 4 MiB (Wk | Wv)
  ushort* WoT  = (ushort*)(ws + ((size_t)38 << 20));   // 2 MiB
  ushort* Qb   = (ushort*)(ws + ((size_t)40 << 20));   // 16 MiB
  ushort* Kb   = (ushort*)(ws + ((size_t)56 << 20));   // 64 MiB
  ushort* VtG  = (ushort*)(ws + ((size_t)120 << 20));  // 64 MiB ([bch][64][256]);
                                                       // [0:16M] doubles as LN out
                                                       // (dead until KV0 epilogue)
  const size_t QROWS = 8192;                           // rows per e-quarter
  ushort* stgP[2] = { stg, stg + QROWS * 1024 };       // ping-pong halves

  // 1. prep: weight transpose/cast + LN (LN out -> VtG[0:16M])
  prep_kernel<<<9216, 256, 0, stream>>>(Wq, Wk, Wv, Wo, h, gamma, beta,
                                        WqT, WkvT, WoT, VtG);

  // 2. Q projection (A = LN out in VtG) + cast e-quarter0 -> stgP[0]
  qproj_cast<<<4608, 256, 0, stream>>>(VtG, WqT, bq, Qb,
                                       0.125f * 1.4426950408889634f,
                                       e, stgP[0]);

  // 3-6. KV GEMM quarter i (reads stgP[i&1]) + fused cast of quarter i+1
  //      (writes stgP[(i+1)&1]) — disjoint ping-pong, cast hidden under GEMM.
  for (int q = 0; q < 4; ++q) {
    const int nblk = (q < 3) ? 2304 : 256;
    gemm_kv256<<<nblk, 512, 0, stream>>>(stgP[q & 1], WkvT, bk, bv,
                                         Kb + (size_t)q * QROWS * 1024, VtG,
                                         q * 8192,
                                         e + (size_t)(q + 1) * QROWS * 1024,
                                         stgP[(q + 1) & 1]);
  }

  // 7. attention: one wave per (b,chunk,head) -> Ob (= stg, dead region)
  attn_kernel<<<512, 256, 0, stream>>>(Qb, Kb, VtG, stg);

  // 8. output projection + shifted residual (f32 out) + folded head_copy
  gemm_oproj<<<764, 256, 0, stream>>>(stg, WoT, bo, out, h);
}

// Round 8
// 497.990 us; speedup vs baseline: 1.0331x; 1.0331x over previous
//
#include <hip/hip_runtime.h>
#include <cstdint>
#include <cstddef>

// ---------------------------------------------------------------------------
// ChunkedCrossAttention: h(4,2048,1024), e(4,32,2,128,1024)
// Pipeline (7 dispatches) — R6 configuration (best measured: 498.2 us):
//   1. prep          = weight transpose/cast + LN (LN out -> VtG[0:16M])
//   2. qproj_cast    = Q-projection (512 blocks) + cast e-half0 (8192 blocks)
//   3. gemm_kv256    (half0)   4. cast_bf16 (half1)   5. gemm_kv256 (half1)
//   6. attn          7. O-proj + shifted residual + folded head_copy
// KV GEMM: proven 256x256 8-phase template (T2 swizzle + T3/T4 counted vmcnt
// + T5 setprio, stage 2/2/2/2) — 848 TF = template ceiling at K=1024.
// attn: one wave per head-job, zero barriers. Workspace exactly 184 MiB.
// Negative results ledger: reg-staged f32 A (R5, -59us), quarter ping-pong
// cast rider (R7, -16us) — do not re-attempt co-scheduled BW work under KV.
// ---------------------------------------------------------------------------

typedef float f32x4 __attribute__((ext_vector_type(4)));
typedef __bf16 bf16x8 __attribute__((ext_vector_type(8)));

static __device__ __forceinline__ ushort f2bf(float f) {
  union { float f; uint32_t u; } x; x.f = f;
  uint32_t r = x.u + 0x7fffu + ((x.u >> 16) & 1u);   // RTNE
  return (ushort)(r >> 16);
}

static __device__ __forceinline__ bf16x8 ld_frag(const ushort* p) {
  union { uint4 u; bf16x8 v; } x;
  x.u = *(const uint4*)p;
  return x.v;
}

// async global->LDS, 16 B per lane (proven working).
static __device__ __forceinline__ void gl2lds16(const ushort* g, ushort* l) {
  __builtin_amdgcn_global_load_lds(
      (const __attribute__((address_space(1))) void*)g,
      (__attribute__((address_space(3))) void*)l,
      16, 0, 0);
}

// ---------------------------------------------------------------------------
// prep: blocks 0..1023  -> weight transpose+cast (z = bx>>8 selects W)
//       blocks 1024..   -> LayerNorm rows (LN out -> lnout, padded w/ zeros)
// ---------------------------------------------------------------------------
__global__ __launch_bounds__(256) void prep_kernel(const float* __restrict__ Wq,
                                                   const float* __restrict__ Wk,
                                                   const float* __restrict__ Wv,
                                                   const float* __restrict__ Wo,
                                                   const float* __restrict__ h,
                                                   const float* __restrict__ gamma,
                                                   const float* __restrict__ beta,
                                                   ushort* __restrict__ WqT,
                                                   ushort* __restrict__ WkvT,
                                                   ushort* __restrict__ WoT,
                                                   ushort* __restrict__ lnout) {
  __shared__ float tile[64][65];
  __shared__ float a1[4], a2[4];
  const int t = threadIdx.x;
  const int bx = blockIdx.x;

  if (bx < 1024) {                       // ---- weight transpose + cast ----
    const int z = bx >> 8, rem = bx & 255;
    const int n0 = (rem & 15) * 64, k0 = (rem >> 4) * 64;
    const float* W; ushort* WT;
    switch (z) {
      case 0:  W = Wq; WT = WqT; break;
      case 1:  W = Wk; WT = WkvT; break;
      case 2:  W = Wv; WT = WkvT + (size_t)1024 * 1024; break;
      default: W = Wo; WT = WoT; break;
    }
#pragma unroll
    for (int i = 0; i < 4; ++i) {
      int lid = i * 256 + t;
      int r = lid >> 4, c4 = (lid & 15) * 4;
      float4 v = *(const float4*)&W[(size_t)(k0 + r) * 1024 + n0 + c4];
      tile[r][c4 + 0] = v.x; tile[r][c4 + 1] = v.y;
      tile[r][c4 + 2] = v.z; tile[r][c4 + 3] = v.w;
    }
    __syncthreads();
#pragma unroll
    for (int i = 0; i < 4; ++i) {
      int lid = i * 256 + t;
      int n = lid >> 4, k4 = (lid & 15) * 4;
      ushort4 o;
      o.x = f2bf(tile[k4 + 0][n]); o.y = f2bf(tile[k4 + 1][n]);
      o.z = f2bf(tile[k4 + 2][n]); o.w = f2bf(tile[k4 + 3][n]);
      *(ushort4*)&WT[(size_t)(n0 + n) * 1024 + k0 + k4] = o;
    }
    return;
  }

  // ---- LayerNorm: lnout[b, s, :] = LN(h[b, 63+s, :]) for s<1985 else 0 ----
  const int bx2 = bx - 1024;
  const int b = bx2 >> 11, s = bx2 & 2047;
  ushort* orow = lnout + (size_t)(b * 2048 + s) * 1024;
  if (s >= 1985) {
    ushort4 z4; z4.x = 0; z4.y = 0; z4.z = 0; z4.w = 0;
    *(ushort4*)&orow[t * 4] = z4;
    return;
  }
  const float* xrow = h + (size_t)(b * 2048 + 63 + s) * 1024;
  float4 x = *(const float4*)&xrow[t * 4];
  float s1 = x.x + x.y + x.z + x.w;
  float s2 = x.x * x.x + x.y * x.y + x.z * x.z + x.w * x.w;
#pragma unroll
  for (int off = 32; off > 0; off >>= 1) {
    s1 += __shfl_xor(s1, off);
    s2 += __shfl_xor(s2, off);
  }
  if ((t & 63) == 0) { a1[t >> 6] = s1; a2[t >> 6] = s2; }
  __syncthreads();
  s1 = a1[0] + a1[1] + a1[2] + a1[3];
  s2 = a2[0] + a2[1] + a2[2] + a2[3];
  const float mu = s1 * (1.0f / 1024.0f);
  const float var = s2 * (1.0f / 1024.0f) - mu * mu;
  const float rstd = rsqrtf(var + 1e-5f);
  float4 g = *(const float4*)&gamma[t * 4];
  float4 be = *(const float4*)&beta[t * 4];
  ushort4 o;
  o.x = f2bf((x.x - mu) * rstd * g.x + be.x);
  o.y = f2bf((x.y - mu) * rstd * g.y + be.y);
  o.z = f2bf((x.z - mu) * rstd * g.z + be.z);
  o.w = f2bf((x.w - mu) * rstd * g.w + be.w);
  *(ushort4*)&orow[t * 4] = o;
}

// ---------------------------------------------------------------------------
// cast f32 -> bf16, 8 elems/thread (half1 path)
// ---------------------------------------------------------------------------
__global__ __launch_bounds__(256) void cast_bf16(const float* __restrict__ x,
                                                 ushort* __restrict__ y) {
  const size_t i = ((size_t)blockIdx.x * 256 + threadIdx.x) * 8;
  float4 a = *(const float4*)&x[i];
  float4 b = *(const float4*)&x[i + 4];
  ushort o[8];
  o[0] = f2bf(a.x); o[1] = f2bf(a.y); o[2] = f2bf(a.z); o[3] = f2bf(a.w);
  o[4] = f2bf(b.x); o[5] = f2bf(b.y); o[6] = f2bf(b.z); o[7] = f2bf(b.w);
  *(uint4*)&y[i] = *(const uint4*)o;
}

// ---------------------------------------------------------------------------
// qproj_cast: blocks <512 = Q projection (128x128 GEMM, bf16 out, scale
// folded = 1/8*log2e); blocks >=512 = e-half0 cast f32->bf16 (8192 blocks).
// Q-proj A (LN out) lives in VtG[0:16M]; cast writes stg -> disjoint.
// ---------------------------------------------------------------------------
__global__ __launch_bounds__(256) void qproj_cast(const ushort* __restrict__ A,
                                                  const ushort* __restrict__ Bt,
                                                  const float* __restrict__ bias,
                                                  ushort* __restrict__ Cbf,
                                                  float scale,
                                                  const float* __restrict__ ex,
                                                  ushort* __restrict__ ey) {
  if (blockIdx.x >= 512) {               // ---- cast path (half 0) ----
    const size_t i = ((size_t)(blockIdx.x - 512) * 256 + threadIdx.x) * 8;
    float4 a = *(const float4*)&ex[i];
    float4 b = *(const float4*)&ex[i + 4];
    ushort o[8];
    o[0] = f2bf(a.x); o[1] = f2bf(a.y); o[2] = f2bf(a.z); o[3] = f2bf(a.w);
    o[4] = f2bf(b.x); o[5] = f2bf(b.y); o[6] = f2bf(b.z); o[7] = f2bf(b.w);
    *(uint4*)&ey[i] = *(const uint4*)o;
    return;
  }
  // ---- Q-proj GEMM path (proven gemm_bf16 MODE0, NT=8) ----
  __shared__ __align__(16) ushort Alds[2][128 * 32];
  __shared__ __align__(16) ushort Blds[2][128 * 32];
  const int t = threadIdx.x;
  const int lane = t & 63, wave = t >> 6;
  const int quad = lane >> 4, l16 = lane & 15;

  const int L = blockIdx.x;
  const int xcd = L & 7, slot = L >> 3;
  const int nt = slot & 7;
  const int mt = xcd * 8 + (slot >> 3);
  const int m0 = mt * 128, n0 = nt * 128;

  const int srow = lane >> 2;
  const int scol = (lane & 3) * 8;
  const int c0 = wave * 2;
  const ushort* gA0 = A  + (size_t)(m0 + c0 * 16 + srow) * 1024 + scol;
  const ushort* gA1 = gA0 + 16 * 1024;
  const ushort* gB0 = Bt + (size_t)(n0 + c0 * 16 + srow) * 1024 + scol;
  const ushort* gB1 = gB0 + 16 * 1024;
  ushort* dA0 = &Alds[0][c0 * 512 + lane * 8];
  ushort* dA1 = dA0 + 512;
  ushort* dB0 = &Blds[0][c0 * 512 + lane * 8];
  ushort* dB1 = dB0 + 512;
  const ptrdiff_t SUB = 128 * 32;

  const int wrow = (wave >> 1) * 64, wcol = (wave & 1) * 64;
  const ushort* pA = &Alds[0][(wrow + l16) * 32 + quad * 8];
  const ushort* pB = &Blds[0][(wcol + l16) * 32 + quad * 8];

  f32x4 zero = {0.f, 0.f, 0.f, 0.f};
  f32x4 acc[4][4];
#pragma unroll
  for (int i = 0; i < 4; ++i)
#pragma unroll
    for (int j = 0; j < 4; ++j) acc[i][j] = zero;

  for (int kb = 0; kb < 16; ++kb) {
    const int ko = kb * 64;
    gl2lds16(gA0 + ko, dA0);         gl2lds16(gA1 + ko, dA1);
    gl2lds16(gA0 + ko + 32, dA0 + SUB); gl2lds16(gA1 + ko + 32, dA1 + SUB);
    gl2lds16(gB0 + ko, dB0);         gl2lds16(gB1 + ko, dB1);
    gl2lds16(gB0 + ko + 32, dB0 + SUB); gl2lds16(gB1 + ko + 32, dB1 + SUB);
    __syncthreads();
#pragma unroll
    for (int sub = 0; sub < 2; ++sub) {
      bf16x8 af[4], bfv[4];
#pragma unroll
      for (int i = 0; i < 4; ++i) af[i]  = ld_frag(pA + sub * SUB + i * 512);
#pragma unroll
      for (int j = 0; j < 4; ++j) bfv[j] = ld_frag(pB + sub * SUB + j * 512);
#pragma unroll
      for (int i = 0; i < 4; ++i)
#pragma unroll
        for (int j = 0; j < 4; ++j)
          acc[i][j] = __builtin_amdgcn_mfma_f32_16x16x32_bf16(af[i], bfv[j], acc[i][j], 0, 0, 0);
    }
    __syncthreads();
  }

#pragma unroll
  for (int mi = 0; mi < 4; ++mi)
#pragma unroll
    for (int mj = 0; mj < 4; ++mj) {
      const int cc = n0 + wcol + mj * 16 + l16;
      const int r0 = m0 + wrow + mi * 16 + quad * 4;
      const float bvb = bias[cc];
#pragma unroll
      for (int rr = 0; rr < 4; ++rr)
        Cbf[(size_t)(r0 + rr) * 1024 + cc] = f2bf((acc[mi][mj][rr] + bvb) * scale);
    }
}

// ---------------------------------------------------------------------------
// 128x128 GEMM: O-proj, f32 out with shifted residual add; blocks >= 512
// perform the head-rows residual copy (folded head_copy).
// ---------------------------------------------------------------------------
__global__ __launch_bounds__(256) void gemm_oproj(const ushort* __restrict__ A,
                                                  const ushort* __restrict__ Bt,
                                                  const float* __restrict__ bias,
                                                  float* __restrict__ Cf,
                                                  const float* __restrict__ resid) {
  if (blockIdx.x >= 512) {       // folded head_copy: rows 0..62 per batch
    const int idx4 = (blockIdx.x - 512) * 256 + threadIdx.x;  // 0..64511
    const int b = idx4 / 16128;
    const int rem = idx4 - b * 16128;
    const size_t o = (size_t)b * 2048 * 1024 + (size_t)rem * 4;
    *(float4*)&Cf[o] = *(const float4*)&resid[o];
    return;
  }
  __shared__ __align__(16) ushort Alds[2][128 * 32];
  __shared__ __align__(16) ushort Blds[2][128 * 32];
  const int t = threadIdx.x;
  const int lane = t & 63, wave = t >> 6;
  const int quad = lane >> 4, l16 = lane & 15;

  const int L = blockIdx.x;
  const int xcd = L & 7, slot = L >> 3;
  const int nt = slot & 7;
  const int mt = xcd * 8 + (slot >> 3);
  const int m0 = mt * 128, n0 = nt * 128;

  const int srow = lane >> 2;
  const int scol = (lane & 3) * 8;
  const int c0 = wave * 2;
  const ushort* gA0 = A  + (size_t)(m0 + c0 * 16 + srow) * 1024 + scol;
  const ushort* gA1 = gA0 + 16 * 1024;
  const ushort* gB0 = Bt + (size_t)(n0 + c0 * 16 + srow) * 1024 + scol;
  const ushort* gB1 = gB0 + 16 * 1024;
  ushort* dA0 = &Alds[0][c0 * 512 + lane * 8];
  ushort* dA1 = dA0 + 512;
  ushort* dB0 = &Blds[0][c0 * 512 + lane * 8];
  ushort* dB1 = dB0 + 512;
  const ptrdiff_t SUB = 128 * 32;

  const int wrow = (wave >> 1) * 64, wcol = (wave & 1) * 64;
  const ushort* pA = &Alds[0][(wrow + l16) * 32 + quad * 8];
  const ushort* pB = &Blds[0][(wcol + l16) * 32 + quad * 8];

  f32x4 zero = {0.f, 0.f, 0.f, 0.f};
  f32x4 acc[4][4];
#pragma unroll
  for (int i = 0; i < 4; ++i)
#pragma unroll
    for (int j = 0; j < 4; ++j) acc[i][j] = zero;

  for (int kb = 0; kb < 16; ++kb) {
    const int ko = kb * 64;
    gl2lds16(gA0 + ko, dA0);         gl2lds16(gA1 + ko, dA1);
    gl2lds16(gA0 + ko + 32, dA0 + SUB); gl2lds16(gA1 + ko + 32, dA1 + SUB);
    gl2lds16(gB0 + ko, dB0);         gl2lds16(gB1 + ko, dB1);
    gl2lds16(gB0 + ko + 32, dB0 + SUB); gl2lds16(gB1 + ko + 32, dB1 + SUB);
    __syncthreads();
#pragma unroll
    for (int sub = 0; sub < 2; ++sub) {
      bf16x8 af[4], bfv[4];
#pragma unroll
      for (int i = 0; i < 4; ++i) af[i]  = ld_frag(pA + sub * SUB + i * 512);
#pragma unroll
      for (int j = 0; j < 4; ++j) bfv[j] = ld_frag(pB + sub * SUB + j * 512);
#pragma unroll
      for (int i = 0; i < 4; ++i)
#pragma unroll
        for (int j = 0; j < 4; ++j)
          acc[i][j] = __builtin_amdgcn_mfma_f32_16x16x32_bf16(af[i], bfv[j], acc[i][j], 0, 0, 0);
    }
    __syncthreads();
  }

#pragma unroll
  for (int mi = 0; mi < 4; ++mi)
#pragma unroll
    for (int mj = 0; mj < 4; ++mj) {
      const int cc = n0 + wcol + mj * 16 + l16;
      const int r0 = m0 + wrow + mi * 16 + quad * 4;
      const float bvb = bias[cc];
#pragma unroll
      for (int rr = 0; rr < 4; ++rr) {
        const int r = r0 + rr;
        const int b = r >> 11, s = r & 2047;
        if (s < 1985) {
          const size_t o = (size_t)(b * 2048 + s + 63) * 1024 + cc;
          Cf[o] = acc[mi][mj][rr] + bvb + resid[o];
        }
      }
    }
}

// ---------------------------------------------------------------------------
// Fused KV GEMM, 256x256 8-phase template; stage schedule 2/2/2/2:
//   P0: A1(t+1), P1: B0(t+2), P2: B1(t+2), P3: A0(t+2).
// Boundary vmcnt(6): oldest 8 = tile t+1's four half-tiles; 6 in flight =
// tile t+2's three staged half-tiles. vmcnt(0) only before final tile.
// ---------------------------------------------------------------------------
__global__ __launch_bounds__(512, 2) void gemm_kv256(const ushort* __restrict__ A,
                                                     const ushort* __restrict__ Bt,
                                                     const float* __restrict__ bk_,
                                                     const float* __restrict__ bv_,
                                                     ushort* __restrict__ Kout,
                                                     ushort* __restrict__ Vtg,
                                                     int mrow_off) {
  __shared__ __align__(16) ushort Alds[4 * 8192];   // 64 KiB
  __shared__ __align__(16) ushort Blds[4 * 8192];   // 64 KiB

  const int t = threadIdx.x;
  const int lane = t & 63, wave = t >> 6;          // 8 waves
  const int wm = wave >> 2, wn = wave & 3;         // 2 x 4
  const int l16 = lane & 15, quad = lane >> 4;

  const int L = blockIdx.x;
  const int xcd = L & 7, slot = L >> 3;
  const int nt = slot & 7, mt = xcd * 8 + (slot >> 3);
  const int m0 = mt * 256, n0 = nt * 256;

  // staging geometry (inverse-swizzled global source, linear LDS dest)
  const int w2 = wave * 2;
  const int srow = lane >> 3;                       // 0..7
  const int lanex = (lane & 7) ^ srow;              // inverse swizzle
  const ushort* gA2 = A  + (size_t)(m0 + w2 * 8 + srow) * 1024 + lanex * 8;
  const ushort* gB2 = Bt + (size_t)(n0 + w2 * 8 + srow) * 1024 + lanex * 8;
  ushort* dA2 = Alds + w2 * 512 + lane * 8;
  ushort* dB2 = Blds + w2 * 512 + lane * 8;

  auto stage_a = [&](int ti, int hh) {
    const ushort* g = gA2 + (size_t)hh * 131072 + (size_t)ti * 64;
    ushort* d = dA2 + ((ti & 1) * 2 + hh) * 8192;
    gl2lds16(g, d);
    gl2lds16(g + 8192, d + 512);
  };
  auto stage_b = [&](int ti, int hh) {
    const ushort* g = gB2 + (size_t)hh * 131072 + (size_t)ti * 64;
    ushort* d = dB2 + ((ti & 1) * 2 + hh) * 8192;
    gl2lds16(g, d);
    gl2lds16(g + 8192, d + 512);
  };

  // read geometry (swizzled): col = (ks^b2)*32 + (quad^(l16&3))*8
  const int b2 = (l16 >> 2) & 1;
  const int qx = (quad ^ (l16 & 3)) << 3;
  const int kof0 = b2 << 5;
  const int kof1 = 32 - kof0;

  f32x4 zero = {0.f, 0.f, 0.f, 0.f};
  f32x4 acc[8][4];
#pragma unroll
  for (int i = 0; i < 8; ++i)
#pragma unroll
    for (int j = 0; j < 4; ++j) acc[i][j] = zero;

  // prologue: tile 0 fully + B0/A0/B1 of tile 1
  stage_b(0, 0); stage_a(0, 0); stage_b(0, 1); stage_a(0, 1);
  stage_b(1, 0); stage_a(1, 0); stage_b(1, 1);
  asm volatile("s_waitcnt vmcnt(6)" ::: "memory");
  __builtin_amdgcn_s_barrier();

  bf16x8 a[4][2], b01[2][2], b23[2][2];

#pragma unroll 2
  for (int tt = 0; tt < 16; ++tt) {
    const int cur = tt & 1;
    const ushort* pa = Alds + (cur * 2 + wm) * 8192 + l16 * 64 + qx;
    const ushort* pb = Blds + (cur * 2 + (wn >> 1)) * 8192 +
                       ((wn & 1) * 64 + l16) * 64 + qx;

    // ================= phase 0: A(mi0-3), B(ni0-1); stage A1(t+1) ========
#pragma unroll
    for (int mi = 0; mi < 4; ++mi) {
      a[mi][0] = ld_frag(pa + mi * 1024 + kof0);
      a[mi][1] = ld_frag(pa + mi * 1024 + kof1);
    }
#pragma unroll
    for (int ni = 0; ni < 2; ++ni) {
      b01[ni][0] = ld_frag(pb + ni * 1024 + kof0);
      b01[ni][1] = ld_frag(pb + ni * 1024 + kof1);
    }
    if (tt < 15) stage_a(tt + 1, 1);
    __builtin_amdgcn_s_barrier();
    asm volatile("s_waitcnt lgkmcnt(0)" ::: "memory");
    __builtin_amdgcn_sched_barrier(0);
    __builtin_amdgcn_s_setprio(1);
#pragma unroll
    for (int mi = 0; mi < 4; ++mi)
#pragma unroll
      for (int ni = 0; ni < 2; ++ni) {
        acc[mi][ni] = __builtin_amdgcn_mfma_f32_16x16x32_bf16(a[mi][0], b01[ni][0], acc[mi][ni], 0, 0, 0);
        acc[mi][ni] = __builtin_amdgcn_mfma_f32_16x16x32_bf16(a[mi][1], b01[ni][1], acc[mi][ni], 0, 0, 0);
      }
    __builtin_amdgcn_s_setprio(0);
    __builtin_amdgcn_s_barrier();

    // ================= phase 1: B(ni2-3); stage B0(t+2) ==================
#pragma unroll
    for (int ni = 0; ni < 2; ++ni) {
      b23[ni][0] = ld_frag(pb + (ni + 2) * 1024 + kof0);
      b23[ni][1] = ld_frag(pb + (ni + 2) * 1024 + kof1);
    }
    if (tt < 14) stage_b(tt + 2, 0);
    __builtin_amdgcn_s_barrier();
    asm volatile("s_waitcnt lgkmcnt(0)" ::: "memory");
    __builtin_amdgcn_sched_barrier(0);
    __builtin_amdgcn_s_setprio(1);
#pragma unroll
    for (int mi = 0; mi < 4; ++mi)
#pragma unroll
      for (int ni = 0; ni < 2; ++ni) {
        acc[mi][ni + 2] = __builtin_amdgcn_mfma_f32_16x16x32_bf16(a[mi][0], b23[ni][0], acc[mi][ni + 2], 0, 0, 0);
        acc[mi][ni + 2] = __builtin_amdgcn_mfma_f32_16x16x32_bf16(a[mi][1], b23[ni][1], acc[mi][ni + 2], 0, 0, 0);
      }
    __builtin_amdgcn_s_setprio(0);
    __builtin_amdgcn_s_barrier();

    // ================= phase 2: A(mi4-7); stage B1(t+2) ==================
#pragma unroll
    for (int mi = 0; mi < 4; ++mi) {
      a[mi][0] = ld_frag(pa + (mi + 4) * 1024 + kof0);
      a[mi][1] = ld_frag(pa + (mi + 4) * 1024 + kof1);
    }
    if (tt < 14) stage_b(tt + 2, 1);
    __builtin_amdgcn_s_barrier();
    asm volatile("s_waitcnt lgkmcnt(0)" ::: "memory");
    __builtin_amdgcn_sched_barrier(0);
    __builtin_amdgcn_s_setprio(1);
#pragma unroll
    for (int mi = 0; mi < 4; ++mi)
#pragma unroll
      for (int ni = 0; ni < 2; ++ni) {
        acc[mi + 4][ni + 2] = __builtin_amdgcn_mfma_f32_16x16x32_bf16(a[mi][0], b23[ni][0], acc[mi + 4][ni + 2], 0, 0, 0);
        acc[mi + 4][ni + 2] = __builtin_amdgcn_mfma_f32_16x16x32_bf16(a[mi][1], b23[ni][1], acc[mi + 4][ni + 2], 0, 0, 0);
      }
    __builtin_amdgcn_s_setprio(0);
    __builtin_amdgcn_s_barrier();

    // ================= phase 3: no reads; stage A0(t+2) ==================
    if (tt < 14) stage_a(tt + 2, 0);
    __builtin_amdgcn_s_barrier();
    __builtin_amdgcn_s_setprio(1);
#pragma unroll
    for (int mi = 0; mi < 4; ++mi)
#pragma unroll
      for (int ni = 0; ni < 2; ++ni) {
        acc[mi + 4][ni] = __builtin_amdgcn_mfma_f32_16x16x32_bf16(a[mi][0], b01[ni][0], acc[mi + 4][ni], 0, 0, 0);
        acc[mi + 4][ni] = __builtin_amdgcn_mfma_f32_16x16x32_bf16(a[mi][1], b01[ni][1], acc[mi + 4][ni], 0, 0, 0);
      }
    __builtin_amdgcn_s_setprio(0);
    // K-tile boundary: counted vmcnt, never 0 in steady state
    if (tt < 15) {
      if (tt == 14) asm volatile("s_waitcnt vmcnt(0)" ::: "memory");
      else          asm volatile("s_waitcnt vmcnt(6)" ::: "memory");
      __builtin_amdgcn_s_barrier();
    }
  }

  // ---- epilogue ----
  const int rbase = m0 + wm * 128 + quad * 4;
  const int cbase = n0 + wn * 64 + l16;
  if (n0 < 1024) {   // K half: row-major bf16 + bk
#pragma unroll
    for (int mi = 0; mi < 8; ++mi)
#pragma unroll
      for (int ni = 0; ni < 4; ++ni) {
        const int cc = cbase + ni * 16;
        const float bb = bk_[cc];
        const int r0 = rbase + mi * 16;
#pragma unroll
        for (int rr = 0; rr < 4; ++rr)
          Kout[(size_t)(r0 + rr) * 1024 + cc] = f2bf(acc[mi][ni][rr] + bb);
      }
  } else {           // V half: transposed per head + bv
#pragma unroll
    for (int mi = 0; mi < 8; ++mi)
#pragma unroll
      for (int ni = 0; ni < 4; ++ni) {
        const int cv = cbase - 1024 + ni * 16;
        const int hh_ = cv >> 6, dd = cv & 63;
        const float bb = bv_[cv];
        const int gr0 = rbase + mi * 16 + mrow_off;
        const int bcl = gr0 >> 8, j0 = gr0 & 255;
        ushort4 o;
        o.x = f2bf(acc[mi][ni][0] + bb);
        o.y = f2bf(acc[mi][ni][1] + bb);
        o.z = f2bf(acc[mi][ni][2] + bb);
        o.w = f2bf(acc[mi][ni][3] + bb);
        *(ushort4*)&Vtg[(size_t)(bcl * 16 + hh_) * 16384 + dd * 256 + j0] = o;
      }
  }
}

// ---------------------------------------------------------------------------
// Attention: ONE WAVE per (b,chunk,head). 512 blocks x 4 independent waves,
// zero barriers. Swapped QK^T, online softmax, P via private per-wave LDS.
// ---------------------------------------------------------------------------
__global__ __launch_bounds__(256, 2) void attn_kernel(const ushort* __restrict__ Qb,
                                                      const ushort* __restrict__ Kb,
                                                      const ushort* __restrict__ Vtg,
                                                      ushort* __restrict__ Ob) {
  __shared__ __align__(16) ushort Plds[4][4096];    // 8 KiB per wave, private

  const int t = threadIdx.x;
  const int lane = t & 63, wave = t >> 6;
  const int quad = lane >> 4, l16 = lane & 15;
  const int hw = blockIdx.x * 4 + wave;             // 0..2047 head-jobs
  const int hd = hw & 15, c = (hw >> 4) & 31, b = hw >> 9;

  const int qrow0 = b * 2048 + c * 64;
  const int kvrow0 = (b * 32 + c) * 256;
  const int colh = hd * 64;
  const ushort* vsrc = Vtg + ((size_t)((b * 32 + c) * 16 + hd)) * 16384;
  char* pw = (char*)&Plds[wave][0];
  const int swz = (l16 & 7) << 4;

  // ---- Q fragments (B-operand): qf[qq][cc] = Q[qq*16+l16][cc*32+quad*8..]
  bf16x8 qf[4][2];
#pragma unroll
  for (int qq = 0; qq < 4; ++qq)
#pragma unroll
    for (int cc = 0; cc < 2; ++cc)
      qf[qq][cc] = ld_frag(&Qb[(size_t)(qrow0 + qq * 16 + l16) * 1024 +
                               colh + cc * 32 + quad * 8]);

  f32x4 zero = {0.f, 0.f, 0.f, 0.f};
  f32x4 Ot[4][4];                                   // [dd][qq], O^T frags
#pragma unroll
  for (int dd = 0; dd < 4; ++dd)
#pragma unroll
    for (int qq = 0; qq < 4; ++qq) Ot[dd][qq] = zero;
  float m[4], l[4];
#pragma unroll
  for (int qq = 0; qq < 4; ++qq) { m[qq] = -1e30f; l[qq] = 0.f; }

  for (int kb = 0; kb < 4; ++kb) {
    // ---- K fragments (A-operand) ----
    bf16x8 kf[4][2];
#pragma unroll
    for (int kk = 0; kk < 4; ++kk)
#pragma unroll
      for (int cc = 0; cc < 2; ++cc)
        kf[kk][cc] = ld_frag(&Kb[(size_t)(kvrow0 + kb * 64 + kk * 16 + l16) * 1024 +
                                 colh + cc * 32 + quad * 8]);

    // ---- St = K Q^T : col=l16=q, row=quad*4+rr=key-within-16 ----
    f32x4 st[4][4];
#pragma unroll
    for (int kk = 0; kk < 4; ++kk)
#pragma unroll
      for (int qq = 0; qq < 4; ++qq) st[kk][qq] = zero;
#pragma unroll
    for (int cc = 0; cc < 2; ++cc)
#pragma unroll
      for (int kk = 0; kk < 4; ++kk)
#pragma unroll
        for (int qq = 0; qq < 4; ++qq)
          st[kk][qq] = __builtin_amdgcn_mfma_f32_16x16x32_bf16(kf[kk][cc], qf[qq][cc], st[kk][qq], 0, 0, 0);

    // ---- V fragments (A-operand for PV); latency hides under softmax ----
    bf16x8 vf[4][2];
#pragma unroll
    for (int dd = 0; dd < 4; ++dd)
#pragma unroll
      for (int cc = 0; cc < 2; ++cc)
        vf[dd][cc] = ld_frag(&vsrc[(dd * 16 + l16) * 256 + kb * 64 + cc * 32 + quad * 8]);

    // ---- online softmax per qq (q = qq*16 + l16) ----
#pragma unroll
    for (int qq = 0; qq < 4; ++qq) {
      float bm = st[0][qq][0];
#pragma unroll
      for (int kk = 0; kk < 4; ++kk)
#pragma unroll
        for (int rr = 0; rr < 4; ++rr) bm = fmaxf(bm, st[kk][qq][rr]);
      bm = fmaxf(bm, __shfl_xor(bm, 16));
      bm = fmaxf(bm, __shfl_xor(bm, 32));
      const float mn = fmaxf(m[qq], bm);
      const float sc = exp2f(m[qq] - mn);
      float bs = 0.f;
#pragma unroll
      for (int kk = 0; kk < 4; ++kk)
#pragma unroll
        for (int rr = 0; rr < 4; ++rr) {
          float p = exp2f(st[kk][qq][rr] - mn);
          st[kk][qq][rr] = p;
          bs += p;
        }
      bs += __shfl_xor(bs, 16);
      bs += __shfl_xor(bs, 32);
      l[qq] = l[qq] * sc + bs;
      m[qq] = mn;
#pragma unroll
      for (int dd = 0; dd < 4; ++dd) Ot[dd][qq] *= sc;
      // P -> LDS at [q][key], swizzled
      const int rowb = (qq * 16 + l16) * 128;
#pragma unroll
      for (int kk = 0; kk < 4; ++kk) {
        uint32_t w0 = (uint32_t)f2bf(st[kk][qq][0]) | ((uint32_t)f2bf(st[kk][qq][1]) << 16);
        uint32_t w1 = (uint32_t)f2bf(st[kk][qq][2]) | ((uint32_t)f2bf(st[kk][qq][3]) << 16);
        const int byte = rowb + ((kk * 32 + quad * 8) ^ swz);
        *(uint32_t*)(pw + byte) = w0;
        *(uint32_t*)(pw + byte + 4) = w1;
      }
    }

    // ---- PV: Ot[dd][qq] += V^T x P ----
#pragma unroll
    for (int qq = 0; qq < 4; ++qq)
#pragma unroll
      for (int cc = 0; cc < 2; ++cc) {
        const int byte = (qq * 16 + l16) * 128 + ((cc * 64 + quad * 16) ^ swz);
        bf16x8 pf = ld_frag((const ushort*)(pw + byte));
#pragma unroll
        for (int dd = 0; dd < 4; ++dd)
          Ot[dd][qq] = __builtin_amdgcn_mfma_f32_16x16x32_bf16(vf[dd][cc], pf, Ot[dd][qq], 0, 0, 0);
      }
  }

  // ---- epilogue: normalize, transpose via LDS (P tile dead), store ----
#pragma unroll
  for (int qq = 0; qq < 4; ++qq) {
    const float inv = 1.0f / l[qq];
    const int rowb = (qq * 16 + l16) * 128;
#pragma unroll
    for (int dd = 0; dd < 4; ++dd) {
      f32x4 v = Ot[dd][qq];
      uint32_t w0 = (uint32_t)f2bf(v[0] * inv) | ((uint32_t)f2bf(v[1] * inv) << 16);
      uint32_t w1 = (uint32_t)f2bf(v[2] * inv) | ((uint32_t)f2bf(v[3] * inv) << 16);
      const int byte = rowb + ((dd * 32 + quad * 8) ^ swz);
      *(uint32_t*)(pw + byte) = w0;
      *(uint32_t*)(pw + byte + 4) = w1;
    }
  }
  // coalesced readout: 8 passes x (8 rows x 8 chunks of 16 B)
#pragma unroll
  for (int p = 0; p < 8; ++p) {
    const int r = p * 8 + (lane >> 3);
    const int ch = lane & 7;
    const int byte = r * 128 + ((ch * 16) ^ ((r & 7) << 4));
    uint4 o = *(const uint4*)(pw + byte);
    *(uint4*)&Ob[(size_t)(qrow0 + r) * 1024 + colh + ch * 8] = o;
  }
}

// ---------------------------------------------------------------------------
extern "C" void kernel_launch(void* const* d_in, const int* in_sizes, int n_in,
                              void* d_out, int out_size, void* d_ws, size_t ws_size,
                              hipStream_t stream) {
  const float* h     = (const float*)d_in[0];
  const float* e     = (const float*)d_in[1];
  const float* Wq    = (const float*)d_in[2];
  const float* bq    = (const float*)d_in[3];
  const float* Wk    = (const float*)d_in[4];
  const float* bk    = (const float*)d_in[5];
  const float* Wv    = (const float*)d_in[6];
  const float* bv    = (const float*)d_in[7];
  const float* Wo    = (const float*)d_in[8];
  const float* bo    = (const float*)d_in[9];
  const float* gamma = (const float*)d_in[10];
  const float* beta  = (const float*)d_in[11];
  float* out = (float*)d_out;

  // Workspace layout (exactly 184 MiB, proven safe):
  char* ws = (char*)d_ws;
  ushort* stg  = (ushort*)(ws + ((size_t)0 << 20));    // 32 MiB (e-cast / attn out)
  ushort* WqT  = (ushort*)(ws + ((size_t)32 << 20));   // 2 MiB
  ushort* WkvT = (ushort*)(ws + ((size_t)34 << 20));   // 4 MiB (Wk | Wv)
  ushort* WoT  = (ushort*)(ws + ((size_t)38 << 20));   // 2 MiB
  ushort* Qb   = (ushort*)(ws + ((size_t)40 << 20));   // 16 MiB
  ushort* Kb   = (ushort*)(ws + ((size_t)56 << 20));   // 64 MiB
  ushort* VtG  = (ushort*)(ws + ((size_t)120 << 20));  // 64 MiB ([bch][64][256]);
                                                       // [0:16M] doubles as LN out
                                                       // (dead until KV0 epilogue)

  // 1. prep: weight transpose/cast + LN (LN out -> VtG[0:16M])
  prep_kernel<<<9216, 256, 0, stream>>>(Wq, Wk, Wv, Wo, h, gamma, beta,
                                        WqT, WkvT, WoT, VtG);

  // 2. Q projection (A = LN out in VtG) CONCURRENT with e-half0 cast -> stg
  qproj_cast<<<8704, 256, 0, stream>>>(VtG, WqT, bq, Qb,
                                       0.125f * 1.4426950408889634f,
                                       e, stg);

  // 3-5. fused K|V projection halves (KV0 overwrites the dead LN region)
  gemm_kv256<<<512, 512, 0, stream>>>(stg, WkvT, bk, bv, Kb, VtG, 0);
  cast_bf16<<<8192, 256, 0, stream>>>(e + (size_t)16384 * 1024, stg);
  gemm_kv256<<<512, 512, 0, stream>>>(stg, WkvT, bk, bv,
                                      Kb + (size_t)16384 * 1024, VtG, 16384);

  // 6. attention: one wave per (b,chunk,head) -> Ob (= stg, dead region)
  attn_kernel<<<512, 256, 0, stream>>>(Qb, Kb, VtG, stg);

  // 7. output projection + shifted residual (f32 out) + folded head_copy
  gemm_oproj<<<764, 256, 0, stream>>>(stg, WoT, bo, out, h);
}